// Round 1
// baseline (195.204 us; speedup 1.0000x reference)
//
#include <hip/hip_runtime.h>
#include <stdint.h>

typedef unsigned short u16t;
typedef short s8v __attribute__((ext_vector_type(8)));
typedef float f4v __attribute__((ext_vector_type(4)));

#define MFMA16 __builtin_amdgcn_mfma_f32_16x16x32_bf16
#define QKN (16*4*512*64)

__device__ __forceinline__ u16t f2bf(float f) {
  unsigned u = __builtin_bit_cast(unsigned, f);
  u += 0x7fffu + ((u >> 16) & 1u);          // RNE
  return (u16t)(u >> 16);
}

// ---------------------------------------------------------------------------
// prep_kernel: fuses the old mask_norm (blockIdx.z == 4) with weff (z < 4).
__global__ __launch_bounds__(256) void prep_kernel(
    const float* __restrict__ Wiqk, const float* __restrict__ Wqi, const float* __restrict__ Wki,
    const float* __restrict__ Wdqk, const float* __restrict__ Wqd, const float* __restrict__ Wkd,
    u16t* __restrict__ weffT, const int* __restrict__ mraw, int* __restrict__ mdst) {
  __shared__ float At[16][65];
  __shared__ float Bt[16][65];
  __shared__ int mode;   // 0=int32, 1=bytes, 2=float32
  const int tid = threadIdx.x;

  if (blockIdx.z == 4) {
    if (tid == 0) mode = 0;
    __syncthreads();
    unsigned v0 = (unsigned)mraw[tid], v1 = (unsigned)mraw[tid + 256];
    if (v0 == 0x3F800000u || v1 == 0x3F800000u) mode = 2;   // benign race
    __syncthreads();
    if (mode == 0 && (v0 > 1u || v1 > 1u)) mode = 1;
    __syncthreads();
    const int g = blockIdx.y * 4 + blockIdx.x;
#pragma unroll
    for (int i = 0; i < 2; ++i) {
      int idx = g * 512 + i * 256 + tid;
      int m;
      if (mode == 2)      m = (((const float*)mraw)[idx] != 0.0f) ? 1 : 0;
      else if (mode == 1) m = ((const unsigned char*)mraw)[idx];
      else                m = mraw[idx];
      mdst[idx] = m;
    }
    return;
  }

  const int n0 = blockIdx.x * 64;
  const int d0 = blockIdx.y * 64;
  const int p  = blockIdx.z;
  const float* A2  = (p == 0) ? Wqi : (p == 1) ? Wki : (p == 2) ? Wqd : Wkd;  // [t][n]
  const float* Wqk = (p < 2) ? Wiqk : Wdqk;                                    // [d][512]
  const int aoff = (p & 1) * 256;
  const int tx = tid & 15, ty = tid >> 4;

  float acc[4][4];
#pragma unroll
  for (int i = 0; i < 4; ++i)
#pragma unroll
    for (int j = 0; j < 4; ++j) acc[i][j] = 0.f;

  for (int k0 = 0; k0 < 256; k0 += 16) {
    __syncthreads();
    {
      int nn = tid & 63, kr = tid >> 6;
#pragma unroll
      for (int pass = 0; pass < 4; ++pass) {
        int kk = kr + pass * 4;
        At[kk][nn] = A2[(size_t)(k0 + kk) * 256 + n0 + nn];
      }
      int kk = tid & 15, dr = tid >> 4;
#pragma unroll
      for (int pass = 0; pass < 4; ++pass) {
        int dd = dr + pass * 16;
        Bt[kk][dd] = Wqk[(size_t)(d0 + dd) * 512 + aoff + k0 + kk];
      }
    }
    __syncthreads();
#pragma unroll
    for (int kk = 0; kk < 16; ++kk) {
      float a[4], b[4];
#pragma unroll
      for (int i = 0; i < 4; ++i) a[i] = At[kk][ty * 4 + i];
#pragma unroll
      for (int j = 0; j < 4; ++j) b[j] = Bt[kk][tx * 4 + j];
#pragma unroll
      for (int i = 0; i < 4; ++i)
#pragma unroll
        for (int j = 0; j < 4; ++j) acc[i][j] = fmaf(a[i], b[j], acc[i][j]);
    }
  }

#pragma unroll
  for (int i = 0; i < 4; ++i) {
    u16t h[4] = {f2bf(acc[i][0]), f2bf(acc[i][1]), f2bf(acc[i][2]), f2bf(acc[i][3])};
    *(uint2*)(&weffT[((size_t)(p * 256 + n0 + ty * 4 + i)) * 256 + d0 + tx * 4]) =
        *(const uint2*)h;
  }
}

// ---------------------------------------------------------------------------
// Projection GEMM: M=8192 (r=b*512+l), N=1024 (p,h,t), K=256.  (unchanged)
__global__ __launch_bounds__(256) void proj_kernel(
    const float* __restrict__ emb, const u16t* __restrict__ weffT,
    const float* __restrict__ bq_inc, const float* __restrict__ bk_inc,
    const float* __restrict__ bq_dec, const float* __restrict__ bk_dec,
    u16t* __restrict__ qk) {
  __shared__ __align__(16) u16t As[128 * 40];
  __shared__ __align__(16) u16t Bs[128 * 40];
  const int t = threadIdx.x;
  const int n0 = blockIdx.x * 128;
  const int r0 = blockIdx.y * 128;
  const int bb = r0 >> 9;
  const int l0 = r0 & 511;
  const int lane = t & 63, wid = t >> 6;
  const int quad = lane >> 4, c15 = lane & 15;
  const int wm = wid >> 1, wn = wid & 1;

  f4v acc[4][4];
#pragma unroll
  for (int i = 0; i < 4; ++i)
#pragma unroll
    for (int j = 0; j < 4; ++j) acc[i][j] = f4v{0.f, 0.f, 0.f, 0.f};

  for (int k0 = 0; k0 < 256; k0 += 32) {
    __syncthreads();
#pragma unroll
    for (int i = 0; i < 2; ++i) {
      int c = t + i * 256;
      int m = c >> 2, off = (c & 3) * 8;
      const float* src = emb + (size_t)((l0 + m) * 16 + bb) * 256 + k0 + off;
      float4 x0 = *(const float4*)src;
      float4 x1 = *(const float4*)(src + 4);
      u16t h[8] = {f2bf(x0.x), f2bf(x0.y), f2bf(x0.z), f2bf(x0.w),
                   f2bf(x1.x), f2bf(x1.y), f2bf(x1.z), f2bf(x1.w)};
      *(uint4*)(&As[m * 40 + off]) = *(const uint4*)h;
      *(uint4*)(&Bs[m * 40 + off]) =
          *(const uint4*)(weffT + (size_t)(n0 + m) * 256 + k0 + off);
    }
    __syncthreads();
    s8v af[4], bf[4];
#pragma unroll
    for (int mi = 0; mi < 4; ++mi)
      af[mi] = *(const s8v*)(&As[(wm * 64 + mi * 16 + c15) * 40 + quad * 8]);
#pragma unroll
    for (int ni = 0; ni < 4; ++ni)
      bf[ni] = *(const s8v*)(&Bs[(wn * 64 + ni * 16 + c15) * 40 + quad * 8]);
#pragma unroll
    for (int mi = 0; mi < 4; ++mi)
#pragma unroll
      for (int ni = 0; ni < 4; ++ni)
        acc[mi][ni] = MFMA16(af[mi], bf[ni], acc[mi][ni], 0, 0, 0);
  }

  const float* biasP[4] = {bq_inc, bk_inc, bq_dec, bk_dec};
#pragma unroll
  for (int ni = 0; ni < 4; ++ni) {
    int n = n0 + wn * 64 + ni * 16 + c15;
    int p = n >> 8, h = (n >> 6) & 3, tt = n & 63, jj = n & 255;
    float bias = biasP[p][jj];
    u16t* dst = qk + (size_t)p * QKN;
#pragma unroll
    for (int mi = 0; mi < 4; ++mi) {
#pragma unroll
      for (int reg = 0; reg < 4; ++reg) {
        int l = l0 + wm * 64 + mi * 16 + quad * 4 + reg;
        dst[((size_t)(bb * 4 + h) * 512 + l) * 64 + tt] = f2bf(acc[mi][ni][reg] + bias);
      }
    }
  }
}

// ---------------------------------------------------------------------------
// Fused attention+epilogue kernel (replaces stats_kernel + final_kernel).
// Block = 16 l-rows x all 512 m for one bb; 8 waves, wave wid owns 64 m.
// Softmax denominator computed block-locally (shfl + cross-wave LDS reduce),
// so QK^T and exp are evaluated exactly ONCE (was twice across stats+final).
__global__ __launch_bounds__(512) void fused_kernel(
    const u16t* __restrict__ qk, const int* __restrict__ mask,
    const int* __restrict__ src_bond, const float* __restrict__ Wc,
    const float* __restrict__ bc, float* __restrict__ out) {
  __shared__ __align__(16) u16t Qs[8 * 16 * 72];
  __shared__ int bondsL[96];
  __shared__ int mlds[512 + 16];
  __shared__ float rpart[2][8][16];
  const int t = threadIdx.x;
  const int l0 = blockIdx.x * 16;
  const int bb = blockIdx.y;

#pragma unroll
  for (int i = 0; i < 2; ++i) {
    int c = t + i * 512;
    int q = c >> 7, row = (c >> 3) & 15, off = (c & 7) * 8;
    const u16t* Qb = qk + (size_t)(2 * (q >> 2)) * QKN;
    *(uint4*)(&Qs[(q * 16 + row) * 72 + off]) =
        *(const uint4*)(Qb + ((size_t)(bb * 4 + (q & 3)) * 512 + l0 + row) * 64 + off);
  }
  mlds[t] = mask[bb * 512 + t];
  if (t < 16) mlds[512 + t] = mask[bb * 512 + l0 + t];
  if (t < 96) bondsL[t] = src_bond[(size_t)(bb * 512 + l0 + t / 6) * 6 + (t % 6)];

  const int lane = t & 63, wid = t >> 6;
  const int quad = lane >> 4, c15 = lane & 15;

  float Wf[16];
#pragma unroll
  for (int i = 0; i < 16; ++i) Wf[i] = Wc[i];

  float dacc[4][4][4];
#pragma unroll
  for (int nt = 0; nt < 4; ++nt)
#pragma unroll
    for (int r = 0; r < 4; ++r)
#pragma unroll
      for (int c = 0; c < 4; ++c) dacc[nt][r][c] = 0.f;

  __syncthreads();

#pragma unroll 1
  for (int q = 0; q < 8; ++q) {
    const int pp = q >> 2, h = q & 3;
    const u16t* Kb = qk + (size_t)(2 * pp + 1) * QKN + (size_t)(bb * 4 + h) * 512 * 64;
    s8v a0 = *(const s8v*)(&Qs[(q * 16 + c15) * 72 + quad * 8]);
    s8v a1 = *(const s8v*)(&Qs[(q * 16 + c15) * 72 + 32 + quad * 8]);

    s8v kb0[4], kb1[4];
#pragma unroll
    for (int nt = 0; nt < 4; ++nt) {
      int m = wid * 64 + nt * 16 + c15;
      kb0[nt] = *(const s8v*)(Kb + (size_t)m * 64 + quad * 8);
      kb1[nt] = *(const s8v*)(Kb + (size_t)m * 64 + 32 + quad * 8);
    }

    float E[4][4];
    float rsum[4] = {0.f, 0.f, 0.f, 0.f};
#pragma unroll
    for (int nt = 0; nt < 4; ++nt) {
      f4v sacc = f4v{0.f, 0.f, 0.f, 0.f};
      sacc = MFMA16(a0, kb0[nt], sacc, 0, 0, 0);
      sacc = MFMA16(a1, kb1[nt], sacc, 0, 0, 0);
      int m = wid * 64 + nt * 16 + c15;
      bool msk = (mlds[m] != 0);
#pragma unroll
      for (int reg = 0; reg < 4; ++reg) {
        float e = msk ? 0.f : __expf(sacc[reg] * 0.125f);
        E[nt][reg] = e;
        rsum[reg] += e;
      }
    }

#pragma unroll
    for (int reg = 0; reg < 4; ++reg) {
#pragma unroll
      for (int off = 1; off < 16; off <<= 1) rsum[reg] += __shfl_xor(rsum[reg], off);
    }
    if (c15 == 0) {
#pragma unroll
      for (int reg = 0; reg < 4; ++reg) rpart[q & 1][wid][quad * 4 + reg] = rsum[reg];
    }
    __syncthreads();

    float inv[4];
    const float sgn = pp ? -1.f : 1.f;
#pragma unroll
    for (int reg = 0; reg < 4; ++reg) {
      float tot = 0.f;
#pragma unroll
      for (int w = 0; w < 8; ++w) tot += rpart[q & 1][w][quad * 4 + reg];
      inv[reg] = sgn / tot;
    }

#pragma unroll
    for (int nt = 0; nt < 4; ++nt) {
#pragma unroll
      for (int reg = 0; reg < 4; ++reg) {
        float P = E[nt][reg] * inv[reg];
#pragma unroll
        for (int c = 0; c < 4; ++c)
          dacc[nt][reg][c] = fmaf(P, Wf[h * 4 + c], dacc[nt][reg][c]);
      }
    }
  }

  float bcF[4];
#pragma unroll
  for (int c = 0; c < 4; ++c) bcF[c] = bc[c];
  const float lgH = logf(0.7f + 1e-6f);
  const float lgM = logf(0.1f + 1e-6f);
  const float lgU = logf(0.25f + 1e-6f);

#pragma unroll
  for (int nt = 0; nt < 4; ++nt) {
    int m = wid * 64 + nt * 16 + c15;
    bool padm = (mlds[m] == 0);
#pragma unroll
    for (int reg = 0; reg < 4; ++reg) {
      int lloc = quad * 4 + reg;
      int l = l0 + lloc;
      bool padl = (mlds[512 + lloc] == 0);
      bool pm = padl && padm;
      int cnt = 0;
#pragma unroll
      for (int j = 0; j < 6; ++j) cnt += (bondsL[lloc * 6 + j] == m) ? 1 : 0;
      int cls = (pm && (m != l)) ? cnt : 0;
      float v[4];
#pragma unroll
      for (int c = 0; c < 4; ++c) {
        float lp = (cls >= 4) ? lgU : ((c == cls) ? lgH : lgM);
        float dv = pm ? 4.f * (dacc[nt][reg][c] + bcF[c]) : 0.f;
        v[c] = lp + dv;
      }
      float4 o = make_float4(v[0], v[1], v[2], v[3]);
      *(float4*)(&out[((size_t)(bb * 512 + l) * 512 + m) * 4]) = o;
    }
  }
}

// ---------------------------------------------------------------------------
extern "C" void kernel_launch(void* const* d_in, const int* in_sizes, int n_in,
                              void* d_out, int out_size, void* d_ws, size_t ws_size,
                              hipStream_t stream) {
  (void)in_sizes; (void)n_in; (void)out_size; (void)ws_size;
  const float* emb      = (const float*)d_in[0];
  const int*   src_bond = (const int*)d_in[1];
  const int*   mask_raw = (const int*)d_in[2];
  const float* W_inc_qk = (const float*)d_in[3];
  const float* Wq_inc   = (const float*)d_in[4];
  const float* bq_inc   = (const float*)d_in[5];
  const float* Wk_inc   = (const float*)d_in[6];
  const float* bk_inc   = (const float*)d_in[7];
  const float* W_dec_qk = (const float*)d_in[8];
  const float* Wq_dec   = (const float*)d_in[9];
  const float* bq_dec   = (const float*)d_in[10];
  const float* Wk_dec   = (const float*)d_in[11];
  const float* bk_dec   = (const float*)d_in[12];
  const float* Wc       = (const float*)d_in[13];
  const float* bc       = (const float*)d_in[14];
  float* out = (float*)d_out;

  char* ws = (char*)d_ws;
  int*   wsMask = (int*)ws;                                        // 32 KiB
  u16t*  weffT  = (u16t*)(ws + 32768);                             // 512 KiB
  u16t*  qk     = (u16t*)(ws + 32768 + 524288);                    // 16 MiB (4 bufs)

  hipLaunchKernelGGL(prep_kernel, dim3(4, 4, 5), dim3(256), 0, stream,
                     W_inc_qk, Wq_inc, Wk_inc, W_dec_qk, Wq_dec, Wk_dec, weffT,
                     mask_raw, wsMask);
  hipLaunchKernelGGL(proj_kernel, dim3(8, 64), dim3(256), 0, stream,
                     emb, weffT, bq_inc, bk_inc, bq_dec, bk_dec, qk);
  hipLaunchKernelGGL(fused_kernel, dim3(32, 16), dim3(512), 0, stream,
                     qk, wsMask, src_bond, Wc, bc, out);
}

// Round 2
// 175.134 us; speedup vs baseline: 1.1146x; 1.1146x over previous
//
#include <hip/hip_runtime.h>
#include <stdint.h>

typedef unsigned short u16t;
typedef short s8v __attribute__((ext_vector_type(8)));
typedef float f4v __attribute__((ext_vector_type(4)));

#define MFMA16 __builtin_amdgcn_mfma_f32_16x16x32_bf16
#define QKN (16*4*512*64)

__device__ __forceinline__ u16t f2bf(float f) {
  unsigned u = __builtin_bit_cast(unsigned, f);
  u += 0x7fffu + ((u >> 16) & 1u);          // RNE
  return (u16t)(u >> 16);
}

// ---------------------------------------------------------------------------
// prep_kernel: fuses mask_norm (blockIdx.z == 4) with the Weff GEMM (z < 4).
__global__ __launch_bounds__(256) void prep_kernel(
    const float* __restrict__ Wiqk, const float* __restrict__ Wqi, const float* __restrict__ Wki,
    const float* __restrict__ Wdqk, const float* __restrict__ Wqd, const float* __restrict__ Wkd,
    u16t* __restrict__ weffT, const int* __restrict__ mraw, int* __restrict__ mdst) {
  __shared__ float At[16][65];
  __shared__ float Bt[16][65];
  __shared__ int mode;   // 0=int32, 1=bytes, 2=float32
  const int tid = threadIdx.x;

  if (blockIdx.z == 4) {
    if (tid == 0) mode = 0;
    __syncthreads();
    unsigned v0 = (unsigned)mraw[tid], v1 = (unsigned)mraw[tid + 256];
    if (v0 == 0x3F800000u || v1 == 0x3F800000u) mode = 2;   // benign race
    __syncthreads();
    if (mode == 0 && (v0 > 1u || v1 > 1u)) mode = 1;
    __syncthreads();
    const int g = blockIdx.y * 4 + blockIdx.x;
#pragma unroll
    for (int i = 0; i < 2; ++i) {
      int idx = g * 512 + i * 256 + tid;
      int m;
      if (mode == 2)      m = (((const float*)mraw)[idx] != 0.0f) ? 1 : 0;
      else if (mode == 1) m = ((const unsigned char*)mraw)[idx];
      else                m = mraw[idx];
      mdst[idx] = m;
    }
    return;
  }

  const int n0 = blockIdx.x * 64;
  const int d0 = blockIdx.y * 64;
  const int p  = blockIdx.z;
  const float* A2  = (p == 0) ? Wqi : (p == 1) ? Wki : (p == 2) ? Wqd : Wkd;  // [t][n]
  const float* Wqk = (p < 2) ? Wiqk : Wdqk;                                    // [d][512]
  const int aoff = (p & 1) * 256;
  const int tx = tid & 15, ty = tid >> 4;

  float acc[4][4];
#pragma unroll
  for (int i = 0; i < 4; ++i)
#pragma unroll
    for (int j = 0; j < 4; ++j) acc[i][j] = 0.f;

  for (int k0 = 0; k0 < 256; k0 += 16) {
    __syncthreads();
    {
      int nn = tid & 63, kr = tid >> 6;
#pragma unroll
      for (int pass = 0; pass < 4; ++pass) {
        int kk = kr + pass * 4;
        At[kk][nn] = A2[(size_t)(k0 + kk) * 256 + n0 + nn];
      }
      int kk = tid & 15, dr = tid >> 4;
#pragma unroll
      for (int pass = 0; pass < 4; ++pass) {
        int dd = dr + pass * 16;
        Bt[kk][dd] = Wqk[(size_t)(d0 + dd) * 512 + aoff + k0 + kk];
      }
    }
    __syncthreads();
#pragma unroll
    for (int kk = 0; kk < 16; ++kk) {
      float a[4], b[4];
#pragma unroll
      for (int i = 0; i < 4; ++i) a[i] = At[kk][ty * 4 + i];
#pragma unroll
      for (int j = 0; j < 4; ++j) b[j] = Bt[kk][tx * 4 + j];
#pragma unroll
      for (int i = 0; i < 4; ++i)
#pragma unroll
        for (int j = 0; j < 4; ++j) acc[i][j] = fmaf(a[i], b[j], acc[i][j]);
    }
  }

#pragma unroll
  for (int i = 0; i < 4; ++i) {
    u16t h[4] = {f2bf(acc[i][0]), f2bf(acc[i][1]), f2bf(acc[i][2]), f2bf(acc[i][3])};
    *(uint2*)(&weffT[((size_t)(p * 256 + n0 + ty * 4 + i)) * 256 + d0 + tx * 4]) =
        *(const uint2*)h;
  }
}

// ---------------------------------------------------------------------------
// Projection GEMM: M=8192 (r=b*512+l), N=1024 (p,h,t), K=256.  (unchanged)
__global__ __launch_bounds__(256) void proj_kernel(
    const float* __restrict__ emb, const u16t* __restrict__ weffT,
    const float* __restrict__ bq_inc, const float* __restrict__ bk_inc,
    const float* __restrict__ bq_dec, const float* __restrict__ bk_dec,
    u16t* __restrict__ qk) {
  __shared__ __align__(16) u16t As[128 * 40];
  __shared__ __align__(16) u16t Bs[128 * 40];
  const int t = threadIdx.x;
  const int n0 = blockIdx.x * 128;
  const int r0 = blockIdx.y * 128;
  const int bb = r0 >> 9;
  const int l0 = r0 & 511;
  const int lane = t & 63, wid = t >> 6;
  const int quad = lane >> 4, c15 = lane & 15;
  const int wm = wid >> 1, wn = wid & 1;

  f4v acc[4][4];
#pragma unroll
  for (int i = 0; i < 4; ++i)
#pragma unroll
    for (int j = 0; j < 4; ++j) acc[i][j] = f4v{0.f, 0.f, 0.f, 0.f};

  for (int k0 = 0; k0 < 256; k0 += 32) {
    __syncthreads();
#pragma unroll
    for (int i = 0; i < 2; ++i) {
      int c = t + i * 256;
      int m = c >> 2, off = (c & 3) * 8;
      const float* src = emb + (size_t)((l0 + m) * 16 + bb) * 256 + k0 + off;
      float4 x0 = *(const float4*)src;
      float4 x1 = *(const float4*)(src + 4);
      u16t h[8] = {f2bf(x0.x), f2bf(x0.y), f2bf(x0.z), f2bf(x0.w),
                   f2bf(x1.x), f2bf(x1.y), f2bf(x1.z), f2bf(x1.w)};
      *(uint4*)(&As[m * 40 + off]) = *(const uint4*)h;
      *(uint4*)(&Bs[m * 40 + off]) =
          *(const uint4*)(weffT + (size_t)(n0 + m) * 256 + k0 + off);
    }
    __syncthreads();
    s8v af[4], bf[4];
#pragma unroll
    for (int mi = 0; mi < 4; ++mi)
      af[mi] = *(const s8v*)(&As[(wm * 64 + mi * 16 + c15) * 40 + quad * 8]);
#pragma unroll
    for (int ni = 0; ni < 4; ++ni)
      bf[ni] = *(const s8v*)(&Bs[(wn * 64 + ni * 16 + c15) * 40 + quad * 8]);
#pragma unroll
    for (int mi = 0; mi < 4; ++mi)
#pragma unroll
      for (int ni = 0; ni < 4; ++ni)
        acc[mi][ni] = MFMA16(af[mi], bf[ni], acc[mi][ni], 0, 0, 0);
  }

  const float* biasP[4] = {bq_inc, bk_inc, bq_dec, bk_dec};
#pragma unroll
  for (int ni = 0; ni < 4; ++ni) {
    int n = n0 + wn * 64 + ni * 16 + c15;
    int p = n >> 8, h = (n >> 6) & 3, tt = n & 63, jj = n & 255;
    float bias = biasP[p][jj];
    u16t* dst = qk + (size_t)p * QKN;
#pragma unroll
    for (int mi = 0; mi < 4; ++mi) {
#pragma unroll
      for (int reg = 0; reg < 4; ++reg) {
        int l = l0 + wm * 64 + mi * 16 + quad * 4 + reg;
        dst[((size_t)(bb * 4 + h) * 512 + l) * 64 + tt] = f2bf(acc[mi][ni][reg] + bias);
      }
    }
  }
}

// ---------------------------------------------------------------------------
// Fused attention+epilogue kernel, latency-pipelined (R2):
//  - XCD-aware block swizzle: all 32 l-tiles of one batch land on one XCD so
//    the 512 KB K panel stays L2-resident (FETCH_SIZE was 2.8x the qk buffer).
//  - K fragments for combo q+1 are issued right after combo q's MFMAs, BEFORE
//    the reduce barrier: the barrier's vmcnt drain absorbs the load latency.
//  - combo-invariant mask bits hoisted to registers; Wc read per combo from
//    LDS with compile-time lane indexing (no runtime-indexed register array).
__global__ __launch_bounds__(512) void fused_kernel(
    const u16t* __restrict__ qk, const int* __restrict__ mask,
    const int* __restrict__ src_bond, const float* __restrict__ Wc,
    const float* __restrict__ bc, float* __restrict__ out) {
  __shared__ __align__(16) u16t Qs[8 * 16 * 72];
  __shared__ int bondsL[96];
  __shared__ int mlds[512 + 16];
  __shared__ __align__(16) float rpart[2][16][8];   // [parity][l-row][wave]
  __shared__ float wlds[16];
  const int t = threadIdx.x;

  // XCD swizzle (bijective: 512 blocks = 8 XCDs x 64). HW round-robins the
  // flat workgroup id across XCDs, so xcd = f&7; give each XCD batches
  // {2k, 2k+1} with all 32 l-tiles each.
  const int f = (int)(blockIdx.x + gridDim.x * blockIdx.y);
  const int j = f >> 3;
  const int bb = (f & 7) * 2 + (j >> 5);
  const int l0 = (j & 31) * 16;

  // ---- stage Q (8 combos x 16 x 64), masks, bonds, Wc into LDS ----
#pragma unroll
  for (int i = 0; i < 2; ++i) {
    int c = t + i * 512;
    int q = c >> 7, row = (c >> 3) & 15, off = (c & 7) * 8;
    const u16t* Qb = qk + (size_t)(2 * (q >> 2)) * QKN;
    *(uint4*)(&Qs[(q * 16 + row) * 72 + off]) =
        *(const uint4*)(Qb + ((size_t)(bb * 4 + (q & 3)) * 512 + l0 + row) * 64 + off);
  }
  mlds[t] = mask[bb * 512 + t];
  if (t < 16) mlds[512 + t] = mask[bb * 512 + l0 + t];
  if (t < 96) bondsL[t] = src_bond[(size_t)(bb * 512 + l0 + t / 6) * 6 + (t % 6)];
  if (t >= 96 && t < 112) wlds[t - 96] = Wc[t - 96];

  const int lane = t & 63, wid = t >> 6;
  const int quad = lane >> 4, c15 = lane & 15;
  const int mbase = wid * 64 + c15;   // + nt*16

  float dacc[4][4][4];   // [nt][reg][class]
#pragma unroll
  for (int nt = 0; nt < 4; ++nt)
#pragma unroll
    for (int r = 0; r < 4; ++r)
#pragma unroll
      for (int c = 0; c < 4; ++c) dacc[nt][r][c] = 0.f;

  // ---- preload K fragments for combo 0 (overlaps the staging barrier) ----
  s8v kb0[4], kb1[4];
  {
    const u16t* Kb = qk + (size_t)1 * QKN + (size_t)(bb * 4 + 0) * 512 * 64;
#pragma unroll
    for (int nt = 0; nt < 4; ++nt) {
      const u16t* row = Kb + (size_t)(mbase + nt * 16) * 64 + quad * 8;
      kb0[nt] = *(const s8v*)row;
      kb1[nt] = *(const s8v*)(row + 32);
    }
  }

  __syncthreads();

  bool mskm[4];
#pragma unroll
  for (int nt = 0; nt < 4; ++nt) mskm[nt] = (mlds[mbase + nt * 16] != 0);

#pragma unroll 1
  for (int q = 0; q < 8; ++q) {
    const int pp = q >> 2, h = q & 3;
    s8v a0 = *(const s8v*)(&Qs[(q * 16 + c15) * 72 + quad * 8]);
    s8v a1 = *(const s8v*)(&Qs[(q * 16 + c15) * 72 + 32 + quad * 8]);

    float wv[4];
#pragma unroll
    for (int c = 0; c < 4; ++c) wv[c] = wlds[h * 4 + c];

    float E[4][4];
    float rsum[4] = {0.f, 0.f, 0.f, 0.f};
#pragma unroll
    for (int nt = 0; nt < 4; ++nt) {
      f4v sacc = f4v{0.f, 0.f, 0.f, 0.f};
      sacc = MFMA16(a0, kb0[nt], sacc, 0, 0, 0);
      sacc = MFMA16(a1, kb1[nt], sacc, 0, 0, 0);
#pragma unroll
      for (int reg = 0; reg < 4; ++reg) {
        float e = mskm[nt] ? 0.f : __expf(sacc[reg] * 0.125f);
        E[nt][reg] = e;
        rsum[reg] += e;
      }
    }

    // prefetch next combo's K fragments; in flight across the barrier drain
    if (q < 7) {
      const int qn = q + 1;
      const u16t* Kb = qk + (size_t)(2 * (qn >> 2) + 1) * QKN
                          + (size_t)(bb * 4 + (qn & 3)) * 512 * 64;
#pragma unroll
      for (int nt = 0; nt < 4; ++nt) {
        const u16t* row = Kb + (size_t)(mbase + nt * 16) * 64 + quad * 8;
        kb0[nt] = *(const s8v*)row;
        kb1[nt] = *(const s8v*)(row + 32);
      }
    }

#pragma unroll
    for (int reg = 0; reg < 4; ++reg) {
#pragma unroll
      for (int off = 1; off < 16; off <<= 1) rsum[reg] += __shfl_xor(rsum[reg], off);
    }
    if (c15 == 0) {
#pragma unroll
      for (int reg = 0; reg < 4; ++reg) rpart[q & 1][quad * 4 + reg][wid] = rsum[reg];
    }
    __syncthreads();

    float inv[4];
    const float sgn = pp ? -1.f : 1.f;
#pragma unroll
    for (int reg = 0; reg < 4; ++reg) {
      const float4* rp = (const float4*)&rpart[q & 1][quad * 4 + reg][0];
      float4 s0 = rp[0], s1 = rp[1];
      inv[reg] = sgn / (s0.x + s0.y + s0.z + s0.w + s1.x + s1.y + s1.z + s1.w);
    }

#pragma unroll
    for (int nt = 0; nt < 4; ++nt) {
#pragma unroll
      for (int reg = 0; reg < 4; ++reg) {
        float P = E[nt][reg] * inv[reg];
#pragma unroll
        for (int c = 0; c < 4; ++c)
          dacc[nt][reg][c] = fmaf(P, wv[c], dacc[nt][reg][c]);
      }
    }
  }

  float bcF[4];
#pragma unroll
  for (int c = 0; c < 4; ++c) bcF[c] = bc[c];
  const float lgH = logf(0.7f + 1e-6f);
  const float lgM = logf(0.1f + 1e-6f);
  const float lgU = logf(0.25f + 1e-6f);

#pragma unroll
  for (int nt = 0; nt < 4; ++nt) {
    int m = mbase + nt * 16;
    bool padm = !mskm[nt];
#pragma unroll
    for (int reg = 0; reg < 4; ++reg) {
      int lloc = quad * 4 + reg;
      int l = l0 + lloc;
      bool padl = (mlds[512 + lloc] == 0);
      bool pm = padl && padm;
      int cnt = 0;
#pragma unroll
      for (int j6 = 0; j6 < 6; ++j6) cnt += (bondsL[lloc * 6 + j6] == m) ? 1 : 0;
      int cls = (pm && (m != l)) ? cnt : 0;
      float v[4];
#pragma unroll
      for (int c = 0; c < 4; ++c) {
        float lp = (cls >= 4) ? lgU : ((c == cls) ? lgH : lgM);
        float dv = pm ? 4.f * (dacc[nt][reg][c] + bcF[c]) : 0.f;
        v[c] = lp + dv;
      }
      float4 o = make_float4(v[0], v[1], v[2], v[3]);
      *(float4*)(&out[((size_t)(bb * 512 + l) * 512 + m) * 4]) = o;
    }
  }
}

// ---------------------------------------------------------------------------
extern "C" void kernel_launch(void* const* d_in, const int* in_sizes, int n_in,
                              void* d_out, int out_size, void* d_ws, size_t ws_size,
                              hipStream_t stream) {
  (void)in_sizes; (void)n_in; (void)out_size; (void)ws_size;
  const float* emb      = (const float*)d_in[0];
  const int*   src_bond = (const int*)d_in[1];
  const int*   mask_raw = (const int*)d_in[2];
  const float* W_inc_qk = (const float*)d_in[3];
  const float* Wq_inc   = (const float*)d_in[4];
  const float* bq_inc   = (const float*)d_in[5];
  const float* Wk_inc   = (const float*)d_in[6];
  const float* bk_inc   = (const float*)d_in[7];
  const float* W_dec_qk = (const float*)d_in[8];
  const float* Wq_dec   = (const float*)d_in[9];
  const float* bq_dec   = (const float*)d_in[10];
  const float* Wk_dec   = (const float*)d_in[11];
  const float* bk_dec   = (const float*)d_in[12];
  const float* Wc       = (const float*)d_in[13];
  const float* bc       = (const float*)d_in[14];
  float* out = (float*)d_out;

  char* ws = (char*)d_ws;
  int*   wsMask = (int*)ws;                                        // 32 KiB
  u16t*  weffT  = (u16t*)(ws + 32768);                             // 512 KiB
  u16t*  qk     = (u16t*)(ws + 32768 + 524288);                    // 16 MiB (4 bufs)

  hipLaunchKernelGGL(prep_kernel, dim3(4, 4, 5), dim3(256), 0, stream,
                     W_inc_qk, Wq_inc, Wk_inc, W_dec_qk, Wq_dec, Wk_dec, weffT,
                     mask_raw, wsMask);
  hipLaunchKernelGGL(proj_kernel, dim3(8, 64), dim3(256), 0, stream,
                     emb, weffT, bq_inc, bk_inc, bq_dec, bk_dec, qk);
  hipLaunchKernelGGL(fused_kernel, dim3(32, 16), dim3(512), 0, stream,
                     qk, wsMask, src_bond, Wc, bc, out);
}